// Round 9
// baseline (532.041 us; speedup 1.0000x reference)
//
#include <hip/hip_runtime.h>
#include <hip/hip_bf16.h>

using bf = __bf16;
typedef __attribute__((ext_vector_type(8))) __bf16 bf16x8;
typedef __attribute__((ext_vector_type(4))) float f32x4;

#define MFMA(a, b, c) __builtin_amdgcn_mfma_f32_16x16x32_bf16((a), (b), (c), 0, 0, 0)
#define GLL16(g, s)                                                         \
    __builtin_amdgcn_global_load_lds(                                       \
        (const __attribute__((address_space(1))) void*)(g),                 \
        (__attribute__((address_space(3))) void*)(s), 16, 0, 0)

// ---------------- fp32 -> bf16 converts (merged, 8 elems/thread) ----------------
static __device__ __forceinline__ void cvt_one(const float* __restrict__ s,
                                               bf* __restrict__ d, int i)
{
    const f32x4 a = ((const f32x4*)s)[2 * i];
    const f32x4 b = ((const f32x4*)s)[2 * i + 1];
    bf16x8 r;
#pragma unroll
    for (int k = 0; k < 4; ++k) { r[k] = (bf)a[k]; r[4 + k] = (bf)b[k]; }
    ((bf16x8*)d)[i] = r;
}

__global__ __launch_bounds__(256) void cvt2(const float* __restrict__ s1, bf* __restrict__ d1, int n1,
                                            const float* __restrict__ s2, bf* __restrict__ d2, int n2)
{
    int i = blockIdx.x * 256 + threadIdx.x;
    if (i < n1) { cvt_one(s1, d1, i); return; }
    i -= n1;
    if (i < n2) cvt_one(s2, d2, i);
}

__global__ __launch_bounds__(256) void cvt3(const float* __restrict__ s1, bf* __restrict__ d1, int n1,
                                            const float* __restrict__ s2, bf* __restrict__ d2, int n2,
                                            const float* __restrict__ s3, bf* __restrict__ d3, int n3)
{
    int i = blockIdx.x * 256 + threadIdx.x;
    if (i < n1) { cvt_one(s1, d1, i); return; }
    i -= n1;
    if (i < n2) { cvt_one(s2, d2, i); return; }
    i -= n2;
    if (i < n3) cvt_one(s3, d3, i);
}

// ---------------- m97-style bf16 128x128 GEMM (R0/R7-exact) ----------------
// EPI 0: bias + L2-norm per 64-col head group, bf16 head-major out.
// EPI 1: bias + fp32 residual, fp32 out row-major.
template <int EPI, int GH, int LGR>
__global__ __launch_bounds__(256) void gemm128(
    const bf* __restrict__ A, const bf* __restrict__ W,
    const float* __restrict__ bias, const float* __restrict__ res,
    void* __restrict__ Cout, int M, int N, int K)
{
    __shared__ __attribute__((aligned(16))) bf As[128 * 32];
    __shared__ __attribute__((aligned(16))) bf Bs[128 * 32];

    const int lane = threadIdx.x & 63;
    const int wave = threadIdx.x >> 6;
    const int lm = lane & 15;
    const int quad = lane >> 4;
    const int row0 = blockIdx.x * 128, col0 = blockIdx.y * 128;
    const int wrow = (wave >> 1) * 64, wcol = (wave & 1) * 64;

    const int sr = lane >> 2;            // 0..15
    const int sc = (lane & 3) * 8;       // elem offset 0,8,16,24
    const bf* Ag = A + (size_t)(row0 + wave * 32 + sr) * K + sc;
    const bf* Wg = W + (size_t)(col0 + wave * 32 + sr) * K + sc;
    bf* AsW = As + wave * 1024;
    bf* BsW = Bs + wave * 1024;

    f32x4 acc[4][4] = {};

    for (int k0 = 0; k0 < K; k0 += 32) {
        GLL16(Ag + k0, AsW);
        GLL16(Ag + (size_t)16 * K + k0, AsW + 512);
        GLL16(Wg + k0, BsW);
        GLL16(Wg + (size_t)16 * K + k0, BsW + 512);
        __syncthreads();

        bf16x8 a[4], b[4];
#pragma unroll
        for (int i = 0; i < 4; ++i)
            a[i] = *(const bf16x8*)(As + (wrow + i * 16 + lm) * 32 + quad * 8);
#pragma unroll
        for (int j = 0; j < 4; ++j)
            b[j] = *(const bf16x8*)(Bs + (wcol + j * 16 + lm) * 32 + quad * 8);
#pragma unroll
        for (int i = 0; i < 4; ++i)
#pragma unroll
            for (int j = 0; j < 4; ++j)
                acc[i][j] = MFMA(a[i], b[j], acc[i][j]);
        __syncthreads();
    }

    float bv[4];
#pragma unroll
    for (int j = 0; j < 4; ++j) bv[j] = bias[col0 + wcol + j * 16 + lm];

    if (EPI == 0) {
        bf* C = (bf*)Cout;
        const int g = (col0 + wcol) >> 6;
#pragma unroll
        for (int i = 0; i < 4; ++i) {
#pragma unroll
            for (int rg = 0; rg < 4; ++rg) {
                float v[4];
                float ss = 0.f;
#pragma unroll
                for (int j = 0; j < 4; ++j) {
                    const float x = acc[i][j][rg] + bv[j];
                    v[j] = x;
                    ss += x * x;
                }
                ss += __shfl_xor(ss, 1, 64);
                ss += __shfl_xor(ss, 2, 64);
                ss += __shfl_xor(ss, 4, 64);
                ss += __shfl_xor(ss, 8, 64);
                const float inv = 1.0f / fmaxf(sqrtf(ss), 1e-12f);
                const int row = row0 + wrow + i * 16 + quad * 4 + rg;
                const int bt = row >> LGR;
                const int rl = row & ((1 << LGR) - 1);
                bf* Cr = C + (((size_t)(bt * GH + g) << LGR) + rl) * 64;
#pragma unroll
                for (int j = 0; j < 4; ++j)
                    Cr[j * 16 + lm] = (bf)(v[j] * inv);
            }
        }
    } else {
        float* C = (float*)Cout;
#pragma unroll
        for (int i = 0; i < 4; ++i) {
#pragma unroll
            for (int rg = 0; rg < 4; ++rg) {
                const int row = row0 + wrow + i * 16 + quad * 4 + rg;
#pragma unroll
                for (int j = 0; j < 4; ++j) {
                    const size_t idx = (size_t)row * N + col0 + wcol + j * 16 + lm;
                    C[idx] = acc[i][j][rg] + bv[j] + res[idx];
                }
            }
        }
    }
}

// ---------------- 256x256 BK=32 bf16 GEMM, 2 blocks/CU ----------------
// Same tile/epilogue as the verified gemm256, restructured for occupancy:
//   LDS 64 KiB (A,B double-buffered 256x32 tiles) -> 2 blocks/CU (16 waves/CU).
//   m97-style 1-ahead double buffer: per tile {stage t+1 -> other buf; ds_read buf t;
//   32 MFMA; vmcnt(0); barrier}.  Race-free: each staged buffer's prior reads retired
//   before the previous barrier; stage(t+1) always targets the buffer not being read.
//   Accumulation order bitwise-identical to BK=64 version (ascending k-chunks of 32).
// Swizzle: 4-slot rows (64 B); LDS[row][slot] holds global slot (slot ^ (row&3));
//   read at slot (quad ^ (lm&3)) recovers logical slot quad.
template <int GH, int LGR>
__global__ __launch_bounds__(512, 4) void gemm256(
    const bf* __restrict__ A, const bf* __restrict__ W,
    const float* __restrict__ bias, bf* __restrict__ C,
    int M, int N, int K)
{
    extern __shared__ __attribute__((aligned(16))) char smem[];
    char* Asm = smem;            // [2 buf][256 rows][64 B]
    char* Bsm = smem + 32768;    // [2 buf][256 rows][64 B]

    const int tid = threadIdx.x;
    const int lane = tid & 63;
    const int lm = lane & 15;
    const int quad = lane >> 4;
    const int wave = tid >> 6;
    const int wm = wave >> 2;        // 0..1  (A half: 128 rows)
    const int wn = wave & 3;         // 0..3  (B quarter: 64 rows)
    const int row0 = blockIdx.x * 256, col0 = blockIdx.y * 256;
    const int NT = K >> 5;           // 16 tiles of BK=32

    // staging: thread t covers dest rows (t>>2) and 128+(t>>2), slot (t&3);
    // source slot pre-swizzled by (row & 3) (identical for both rows: +128 ≡ 0 mod 4)
    const int trow = tid >> 2;
    const int sswz = (tid & 3) ^ (trow & 3);
    const bf* Ath = A + (size_t)(row0 + trow) * K + sswz * 8;
    const bf* Wth = W + (size_t)(col0 + trow) * K + sswz * 8;

    const char* aBase = Asm + wm * 8192;   // + (f*16+lm)*64 + swz*16
    const char* bBase = Bsm + wn * 4096;
    const int sk = ((quad ^ (lm & 3)) << 4);

    f32x4 acc[8][4] = {};

    auto stage = [&](int kt) {
        const int bo = (kt & 1) * 16384;
        const int ko = kt * 32;
        GLL16(Ath + ko, Asm + bo + tid * 16);
        GLL16(Ath + (size_t)128 * K + ko, Asm + bo + 8192 + tid * 16);
        GLL16(Wth + ko, Bsm + bo + tid * 16);
        GLL16(Wth + (size_t)128 * K + ko, Bsm + bo + 8192 + tid * 16);
    };

    // prologue: tile 0 into buf0
    stage(0);
    asm volatile("s_waitcnt vmcnt(0)" ::: "memory");
    __builtin_amdgcn_s_barrier();

    for (int t = 0; t < NT; ++t) {
        if (t + 1 < NT) stage(t + 1);          // other buffer: no race
        const int bo = (t & 1) * 16384;
        bf16x8 a[4], b[4];
#pragma unroll
        for (int j = 0; j < 4; ++j)
            b[j] = *(const bf16x8*)(bBase + bo + (j * 16 + lm) * 64 + sk);
#pragma unroll
        for (int mm = 0; mm < 4; ++mm)
            a[mm] = *(const bf16x8*)(aBase + bo + (mm * 16 + lm) * 64 + sk);
        __builtin_amdgcn_s_setprio(1);
#pragma unroll
        for (int mm = 0; mm < 4; ++mm)
#pragma unroll
            for (int j = 0; j < 4; ++j)
                acc[mm][j] = MFMA(a[mm], b[j], acc[mm][j]);
        __builtin_amdgcn_s_setprio(0);
#pragma unroll
        for (int mm = 0; mm < 4; ++mm)
            a[mm] = *(const bf16x8*)(aBase + bo + ((4 + mm) * 16 + lm) * 64 + sk);
        __builtin_amdgcn_s_setprio(1);
#pragma unroll
        for (int mm = 0; mm < 4; ++mm)
#pragma unroll
            for (int j = 0; j < 4; ++j)
                acc[4 + mm][j] = MFMA(a[mm], b[j], acc[4 + mm][j]);
        __builtin_amdgcn_s_setprio(0);
        asm volatile("s_waitcnt vmcnt(0)" ::: "memory");  // tile t+1 fully landed
        __builtin_amdgcn_s_barrier();
    }

    // ---- epilogue: bias + L2-norm per 64-col head, head-major bf16 out (unchanged) ----
    float bv[4];
#pragma unroll
    for (int j = 0; j < 4; ++j) bv[j] = bias[col0 + wn * 64 + j * 16 + lm];
    const int g = (col0 + wn * 64) >> 6;
#pragma unroll
    for (int m = 0; m < 8; ++m) {
#pragma unroll
        for (int rg = 0; rg < 4; ++rg) {
            float v[4];
            float ss = 0.f;
#pragma unroll
            for (int j = 0; j < 4; ++j) {
                const float x = acc[m][j][rg] + bv[j];
                v[j] = x;
                ss += x * x;
            }
            ss += __shfl_xor(ss, 1, 64);
            ss += __shfl_xor(ss, 2, 64);
            ss += __shfl_xor(ss, 4, 64);
            ss += __shfl_xor(ss, 8, 64);
            const float inv = 1.0f / fmaxf(sqrtf(ss), 1e-12f);
            const int row = row0 + wm * 128 + m * 16 + quad * 4 + rg;
            const int bt = row >> LGR;
            const int rl = row & ((1 << LGR) - 1);
            bf* Cr = C + (((size_t)(bt * GH + g) << LGR) + rl) * 64;
#pragma unroll
            for (int j = 0; j < 4; ++j)
                Cr[j * 16 + lm] = (bf)(v[j] * inv);
        }
    }
}

// ---------------- flash-style cosine attention, NO-MAX softmax (R0-exact) ----------------
__global__ __launch_bounds__(256, 4) void attn(
    const bf* __restrict__ qn, const bf* __restrict__ kvn, bf* __restrict__ X)
{
    __shared__ __attribute__((aligned(16))) bf Kt[128 * 72];
    __shared__ __attribute__((aligned(16))) bf Vt[64 * 136];
    __shared__ __attribute__((aligned(16))) bf Ps[4][16 * 40];

    const int qb = blockIdx.x >> 9;
    const int rb = blockIdx.x & 511;
    const int bt = rb >> 3;
    const int h = rb & 7;
    const int tid = threadIdx.x;
    const int lane = tid & 63;
    const int wave = tid >> 6;
    const int lm = lane & 15;
    const int quad = lane >> 4;

    const bf* qh = qn + ((size_t)(bt * 8 + h) * 256 + qb * 128) * 64;
    const bf* kh = kvn + (size_t)(bt * 16 + h) * 512 * 64;
    const bf* vh = kvn + (size_t)(bt * 16 + 8 + h) * 512 * 64;

    const int srow = tid >> 1;
    const int sseg = (tid & 1) * 32;

    f32x4 o[2][4] = {};
    float sum[2][4] = {};
    bf* Pw = &Ps[wave][0];

    for (int t = 0; t < 4; ++t) {
        {
            const bf* kr = kh + (size_t)(t * 128 + srow) * 64 + sseg;
            bf* kd = Kt + srow * 72 + sseg;
#pragma unroll
            for (int j = 0; j < 4; ++j)
                *(bf16x8*)(kd + j * 8) = *(const bf16x8*)(kr + j * 8);

            const bf* vr = vh + (size_t)(t * 128 + srow) * 64 + sseg;
            bf16x8 vv[4];
#pragma unroll
            for (int j = 0; j < 4; ++j) vv[j] = *(const bf16x8*)(vr + j * 8);
#pragma unroll
            for (int j = 0; j < 4; ++j)
#pragma unroll
                for (int e = 0; e < 8; ++e)
                    Vt[(sseg + j * 8 + e) * 136 + srow] = vv[j][e];
        }
        __syncthreads();

#pragma unroll
        for (int c = 0; c < 2; ++c) {
            const int r0 = wave * 32 + c * 16;
            const bf* qp = qh + (size_t)(r0 + lm) * 64 + quad * 8;
            const bf16x8 a0 = *(const bf16x8*)qp;
            const bf16x8 a1 = *(const bf16x8*)(qp + 32);

            f32x4 s[8];
#pragma unroll
            for (int nt = 0; nt < 8; ++nt) {
                const bf16x8 k0 = *(const bf16x8*)(&Kt[(nt * 16 + lm) * 72 + quad * 8]);
                const bf16x8 k1 = *(const bf16x8*)(&Kt[(nt * 16 + lm) * 72 + 32 + quad * 8]);
                f32x4 z = {};
                z = MFMA(a0, k0, z);
                s[nt] = MFMA(a1, k1, z);
            }

            for (int ntp = 0; ntp < 4; ++ntp) {
#pragma unroll
                for (int tt = 0; tt < 2; ++tt)
#pragma unroll
                    for (int rr = 0; rr < 4; ++rr) {
                        const float e = __expf(s[ntp * 2 + tt][rr] * 0.125f);
                        sum[c][rr] += e;
                        Pw[(quad * 4 + rr) * 40 + tt * 16 + lm] = (bf)e;
                    }
                const bf16x8 ap = *(const bf16x8*)(&Pw[lm * 40 + quad * 8]);
#pragma unroll
                for (int dt = 0; dt < 4; ++dt) {
                    const bf16x8 bv = *(const bf16x8*)(&Vt[(dt * 16 + lm) * 136 + ntp * 32 + quad * 8]);
                    o[c][dt] = MFMA(ap, bv, o[c][dt]);
                }
            }
        }
        __syncthreads();
    }

#pragma unroll
    for (int c = 0; c < 2; ++c) {
        float inv[4];
#pragma unroll
        for (int rr = 0; rr < 4; ++rr) {
            float sm = sum[c][rr];
            sm += __shfl_xor(sm, 1, 64);
            sm += __shfl_xor(sm, 2, 64);
            sm += __shfl_xor(sm, 4, 64);
            sm += __shfl_xor(sm, 8, 64);
            inv[rr] = 1.0f / sm;
        }
        bf* Xp = X + ((size_t)bt * 256 + qb * 128 + wave * 32 + c * 16) * 512 + h * 64;
#pragma unroll
        for (int dt = 0; dt < 4; ++dt)
#pragma unroll
            for (int rr = 0; rr < 4; ++rr)
                Xp[(size_t)(quad * 4 + rr) * 512 + dt * 16 + lm] = (bf)(o[c][dt][rr] * inv[rr]);
    }
}

extern "C" void kernel_launch(void* const* d_in, const int* in_sizes, int n_in,
                              void* d_out, int out_size, void* d_ws, size_t ws_size,
                              hipStream_t stream)
{
    const float* q   = (const float*)d_in[0];  // (8,8,256,512) fp32
    const float* kv  = (const float*)d_in[1];  // (8,8,512,512) fp32
    const float* Wq  = (const float*)d_in[2];  // (512,512) fp32
    const float* bq  = (const float*)d_in[3];  // (512) fp32
    const float* Wkv = (const float*)d_in[4];  // (1024,512) fp32
    const float* bkv = (const float*)d_in[5];  // (1024) fp32
    const float* Wm  = (const float*)d_in[6];  // (512,512) fp32
    const float* bm  = (const float*)d_in[7];  // (512) fp32
    float* out = (float*)d_out;                // (8,8,256,512) fp32 (32 MiB)

    // R7-exact buffer map:
    // ws:   kvb [0,32 MiB) (dead after step 2)      kvn [32,96 MiB)
    //       wqb [0,0.5 MiB) (written step 3, after kvb dead)
    //       wmb [16,16.5 MiB) (written step 3, survives: X is [0,16))
    //       X   [0,16 MiB) (written step 5, after wqb dead)
    // d_out: wkvb [0,1 MiB) (dead after step 2); qb [0,16 MiB) (written step 3);
    //        qn [16,32 MiB); step 6 rewrites all of d_out with fp32 out.
    char* ws = (char*)d_ws;
    bf* kvb = (bf*)ws;
    bf* kvn = (bf*)(ws + (size_t)(32 << 20));
    bf* wqb = (bf*)ws;
    bf* wmb = (bf*)(ws + (size_t)(16 << 20));
    bf* X   = (bf*)ws;
    char* dob = (char*)d_out;
    bf* wkvb = (bf*)dob;
    bf* qb   = (bf*)dob;
    bf* qn   = (bf*)(dob + (size_t)(16 << 20));

    {
        auto k0 = gemm256<16, 9>;
        (void)hipFuncSetAttribute((const void*)k0, hipFuncAttributeMaxDynamicSharedMemorySize, 65536);
    }

    // 1. kv + Wkv -> bf16
    cvt2<<<dim3(8448), 256, 0, stream>>>(kv, kvb, 2097152, Wkv, wkvb, 65536);
    // 2. KV projection + bias + fused L2-norm -> head-major kvn  [BK=32, 2 blocks/CU]
    gemm256<16, 9><<<dim3(128, 4), 512, 65536, stream>>>(kvb, wkvb, bkv, kvn, 32768, 1024, 512);
    // 3. q, Wq, Wm -> bf16
    cvt3<<<dim3(4352), 256, 0, stream>>>(q, qb, 1048576, Wq, wqb, 32768, Wm, wmb, 32768);
    // 4. Q projection + bias + fused L2-norm -> head-major qn  [R0-exact gemm128]
    gemm128<0, 8, 8><<<dim3(128, 4), 256, 0, stream>>>(qb, wqb, bq, nullptr, qn, 16384, 512, 512);
    // 5. no-max flash cosine attention  [R0-exact]
    attn<<<dim3(1024), 256, 0, stream>>>(qn, kvn, X);
    // 6. output projection + bias + fp32 residual -> fp32 out  [R0-exact gemm128]
    gemm128<1, 0, 0><<<dim3(128, 4), 256, 0, stream>>>(X, wmb, bm, q, out, 16384, 512, 512);
}

// Round 10
// 287.618 us; speedup vs baseline: 1.8498x; 1.8498x over previous
//
#include <hip/hip_runtime.h>
#include <hip/hip_bf16.h>

using bf = __bf16;
typedef __attribute__((ext_vector_type(8))) __bf16 bf16x8;
typedef __attribute__((ext_vector_type(4))) float f32x4;

#define MFMA(a, b, c) __builtin_amdgcn_mfma_f32_16x16x32_bf16((a), (b), (c), 0, 0, 0)
#define GLL16(g, s)                                                         \
    __builtin_amdgcn_global_load_lds(                                       \
        (const __attribute__((address_space(1))) void*)(g),                 \
        (__attribute__((address_space(3))) void*)(s), 16, 0, 0)

// ---------------- fp32 -> bf16 converts (merged, 8 elems/thread) ----------------
static __device__ __forceinline__ void cvt_one(const float* __restrict__ s,
                                               bf* __restrict__ d, int i)
{
    const f32x4 a = ((const f32x4*)s)[2 * i];
    const f32x4 b = ((const f32x4*)s)[2 * i + 1];
    bf16x8 r;
#pragma unroll
    for (int k = 0; k < 4; ++k) { r[k] = (bf)a[k]; r[4 + k] = (bf)b[k]; }
    ((bf16x8*)d)[i] = r;
}

__global__ __launch_bounds__(256) void cvt2(const float* __restrict__ s1, bf* __restrict__ d1, int n1,
                                            const float* __restrict__ s2, bf* __restrict__ d2, int n2)
{
    int i = blockIdx.x * 256 + threadIdx.x;
    if (i < n1) { cvt_one(s1, d1, i); return; }
    i -= n1;
    if (i < n2) cvt_one(s2, d2, i);
}

__global__ __launch_bounds__(256) void cvt3(const float* __restrict__ s1, bf* __restrict__ d1, int n1,
                                            const float* __restrict__ s2, bf* __restrict__ d2, int n2,
                                            const float* __restrict__ s3, bf* __restrict__ d3, int n3)
{
    int i = blockIdx.x * 256 + threadIdx.x;
    if (i < n1) { cvt_one(s1, d1, i); return; }
    i -= n1;
    if (i < n2) { cvt_one(s2, d2, i); return; }
    i -= n2;
    if (i < n3) cvt_one(s3, d3, i);
}

// ---------------- m97-style bf16 128x128 GEMM (R0/R7-exact) ----------------
// EPI 0: bias + L2-norm per 64-col head group, bf16 head-major out.
// EPI 1: bias + fp32 residual, fp32 out row-major.
template <int EPI, int GH, int LGR>
__global__ __launch_bounds__(256) void gemm128(
    const bf* __restrict__ A, const bf* __restrict__ W,
    const float* __restrict__ bias, const float* __restrict__ res,
    void* __restrict__ Cout, int M, int N, int K)
{
    __shared__ __attribute__((aligned(16))) bf As[128 * 32];
    __shared__ __attribute__((aligned(16))) bf Bs[128 * 32];

    const int lane = threadIdx.x & 63;
    const int wave = threadIdx.x >> 6;
    const int lm = lane & 15;
    const int quad = lane >> 4;
    const int row0 = blockIdx.x * 128, col0 = blockIdx.y * 128;
    const int wrow = (wave >> 1) * 64, wcol = (wave & 1) * 64;

    const int sr = lane >> 2;            // 0..15
    const int sc = (lane & 3) * 8;       // elem offset 0,8,16,24
    const bf* Ag = A + (size_t)(row0 + wave * 32 + sr) * K + sc;
    const bf* Wg = W + (size_t)(col0 + wave * 32 + sr) * K + sc;
    bf* AsW = As + wave * 1024;
    bf* BsW = Bs + wave * 1024;

    f32x4 acc[4][4] = {};

    for (int k0 = 0; k0 < K; k0 += 32) {
        GLL16(Ag + k0, AsW);
        GLL16(Ag + (size_t)16 * K + k0, AsW + 512);
        GLL16(Wg + k0, BsW);
        GLL16(Wg + (size_t)16 * K + k0, BsW + 512);
        __syncthreads();

        bf16x8 a[4], b[4];
#pragma unroll
        for (int i = 0; i < 4; ++i)
            a[i] = *(const bf16x8*)(As + (wrow + i * 16 + lm) * 32 + quad * 8);
#pragma unroll
        for (int j = 0; j < 4; ++j)
            b[j] = *(const bf16x8*)(Bs + (wcol + j * 16 + lm) * 32 + quad * 8);
#pragma unroll
        for (int i = 0; i < 4; ++i)
#pragma unroll
            for (int j = 0; j < 4; ++j)
                acc[i][j] = MFMA(a[i], b[j], acc[i][j]);
        __syncthreads();
    }

    float bv[4];
#pragma unroll
    for (int j = 0; j < 4; ++j) bv[j] = bias[col0 + wcol + j * 16 + lm];

    if (EPI == 0) {
        bf* C = (bf*)Cout;
        const int g = (col0 + wcol) >> 6;
#pragma unroll
        for (int i = 0; i < 4; ++i) {
#pragma unroll
            for (int rg = 0; rg < 4; ++rg) {
                float v[4];
                float ss = 0.f;
#pragma unroll
                for (int j = 0; j < 4; ++j) {
                    const float x = acc[i][j][rg] + bv[j];
                    v[j] = x;
                    ss += x * x;
                }
                ss += __shfl_xor(ss, 1, 64);
                ss += __shfl_xor(ss, 2, 64);
                ss += __shfl_xor(ss, 4, 64);
                ss += __shfl_xor(ss, 8, 64);
                const float inv = 1.0f / fmaxf(sqrtf(ss), 1e-12f);
                const int row = row0 + wrow + i * 16 + quad * 4 + rg;
                const int bt = row >> LGR;
                const int rl = row & ((1 << LGR) - 1);
                bf* Cr = C + (((size_t)(bt * GH + g) << LGR) + rl) * 64;
#pragma unroll
                for (int j = 0; j < 4; ++j)
                    Cr[j * 16 + lm] = (bf)(v[j] * inv);
            }
        }
    } else {
        float* C = (float*)Cout;
#pragma unroll
        for (int i = 0; i < 4; ++i) {
#pragma unroll
            for (int rg = 0; rg < 4; ++rg) {
                const int row = row0 + wrow + i * 16 + quad * 4 + rg;
#pragma unroll
                for (int j = 0; j < 4; ++j) {
                    const size_t idx = (size_t)row * N + col0 + wcol + j * 16 + lm;
                    C[idx] = acc[i][j][rg] + bv[j] + res[idx];
                }
            }
        }
    }
}

// ---------------- KV GEMM: 128x128 tile, BK=64, dbuf, 2 blocks/CU ----------------
// 256 thr / 4 waves (2Mx2N), per-wave 64x64 -> acc[4][4] = 64 regs (no spill at 256-cap).
// LDS 64 KiB dynamic (A,B double-buffered 128x64 bf16 tiles) -> exactly 2 blocks/CU;
// the co-resident block hides this block's vmcnt(0)+barrier drain (m97 mechanism).
// 128-B rows (full 32-bank span) + gemm256's verified swizzle: phys slot = logical ^ (row&7),
// applied on the GLL *source* (LDS dest linear), recovered on the ds_read side -> 0 conflicts.
// 1-ahead prefetch into the opposite buffer is race-free: that buffer's reads retired
// before the previous __syncthreads(). Accumulation order bitwise-identical (ascending k/32).
// Grid (8,256): bx=col-block, by=row-block -> 8 adjacent blocks share one A panel (L3-hot).
template <int GH, int LGR>
__global__ __launch_bounds__(256, 2) void gemmkv(
    const bf* __restrict__ A, const bf* __restrict__ W,
    const float* __restrict__ bias, bf* __restrict__ C, int K)
{
    extern __shared__ __attribute__((aligned(16))) char smem[];
    char* Asm = smem;            // [2 buf][128 rows][128 B]
    char* Bsm = smem + 32768;

    const int tid = threadIdx.x;
    const int lane = tid & 63;
    const int lm = lane & 15;
    const int quad = lane >> 4;
    const int wave = tid >> 6;
    const int wm = wave >> 1;        // 0..1 (A half)
    const int wn = wave & 1;         // 0..1 (B half)
    const int col0 = blockIdx.x * 128, row0 = blockIdx.y * 128;
    const int NT = K >> 6;           // 8 tiles of BK=64

    // staging: unit u = tid + 256*i covers row u>>3 (= tr+32i), phys slot u&7 (= tid&7);
    // source slot pre-swizzled: s ^ ((tr+32i)&7) = s ^ (tr&7)  (32i = 0 mod 8)
    const int tr = tid >> 3;
    const int sswz = (tid & 7) ^ (tr & 7);
    const bf* Ath = A + (size_t)(row0 + tr) * K + sswz * 8;
    const bf* Wth = W + (size_t)(col0 + tr) * K + sswz * 8;
    const int doff = tr * 128 + (tid & 7) * 16;

    const char* aBase = Asm + (wm * 64 + lm) * 128;
    const char* bBase = Bsm + (wn * 64 + lm) * 128;
    const int skz0 = ((quad ^ (lm & 7)) << 4);
    const int skz1 = (((4 + quad) ^ (lm & 7)) << 4);

    f32x4 acc[4][4] = {};

    auto stage = [&](int kt) {
        const int bo = (kt & 1) * 16384;
        const int ko = kt * 64;
#pragma unroll
        for (int i = 0; i < 4; ++i) {
            GLL16(Ath + (size_t)(32 * i) * K + ko, Asm + bo + i * 4096 + doff);
            GLL16(Wth + (size_t)(32 * i) * K + ko, Bsm + bo + i * 4096 + doff);
        }
    };

    // prologue: tile 0 into buf0
    stage(0);
    __syncthreads();

    for (int t = 0; t < NT; ++t) {
        if (t + 1 < NT) stage(t + 1);       // opposite buffer: race-free
        const int bo = (t & 1) * 16384;
        bf16x8 a[4], b[4];
#pragma unroll
        for (int f = 0; f < 4; ++f) {
            a[f] = *(const bf16x8*)(aBase + bo + f * 2048 + skz0);
            b[f] = *(const bf16x8*)(bBase + bo + f * 2048 + skz0);
        }
        __builtin_amdgcn_s_setprio(1);
#pragma unroll
        for (int f = 0; f < 4; ++f)
#pragma unroll
            for (int j = 0; j < 4; ++j)
                acc[f][j] = MFMA(a[f], b[j], acc[f][j]);
        __builtin_amdgcn_s_setprio(0);
#pragma unroll
        for (int f = 0; f < 4; ++f) {
            a[f] = *(const bf16x8*)(aBase + bo + f * 2048 + skz1);
            b[f] = *(const bf16x8*)(bBase + bo + f * 2048 + skz1);
        }
        __builtin_amdgcn_s_setprio(1);
#pragma unroll
        for (int f = 0; f < 4; ++f)
#pragma unroll
            for (int j = 0; j < 4; ++j)
                acc[f][j] = MFMA(a[f], b[j], acc[f][j]);
        __builtin_amdgcn_s_setprio(0);
        __syncthreads();                    // drains vmcnt(0): tile t+1 landed
    }

    // ---- epilogue: bias + L2-norm per 64-col head, head-major bf16 out ----
    const int wrow = wm * 64, wcol = wn * 64;
    float bv[4];
#pragma unroll
    for (int j = 0; j < 4; ++j) bv[j] = bias[col0 + wcol + j * 16 + lm];
    const int g = (col0 + wcol) >> 6;
#pragma unroll
    for (int i = 0; i < 4; ++i) {
#pragma unroll
        for (int rg = 0; rg < 4; ++rg) {
            float v[4];
            float ss = 0.f;
#pragma unroll
            for (int j = 0; j < 4; ++j) {
                const float x = acc[i][j][rg] + bv[j];
                v[j] = x;
                ss += x * x;
            }
            ss += __shfl_xor(ss, 1, 64);
            ss += __shfl_xor(ss, 2, 64);
            ss += __shfl_xor(ss, 4, 64);
            ss += __shfl_xor(ss, 8, 64);
            const float inv = 1.0f / fmaxf(sqrtf(ss), 1e-12f);
            const int row = row0 + wrow + i * 16 + quad * 4 + rg;
            const int bt = row >> LGR;
            const int rl = row & ((1 << LGR) - 1);
            bf* Cr = C + (((size_t)(bt * GH + g) << LGR) + rl) * 64;
#pragma unroll
            for (int j = 0; j < 4; ++j)
                Cr[j * 16 + lm] = (bf)(v[j] * inv);
        }
    }
}

// ---------------- flash-style cosine attention, NO-MAX softmax (R0-exact) ----------------
__global__ __launch_bounds__(256, 4) void attn(
    const bf* __restrict__ qn, const bf* __restrict__ kvn, bf* __restrict__ X)
{
    __shared__ __attribute__((aligned(16))) bf Kt[128 * 72];
    __shared__ __attribute__((aligned(16))) bf Vt[64 * 136];
    __shared__ __attribute__((aligned(16))) bf Ps[4][16 * 40];

    const int qb = blockIdx.x >> 9;
    const int rb = blockIdx.x & 511;
    const int bt = rb >> 3;
    const int h = rb & 7;
    const int tid = threadIdx.x;
    const int lane = tid & 63;
    const int wave = tid >> 6;
    const int lm = lane & 15;
    const int quad = lane >> 4;

    const bf* qh = qn + ((size_t)(bt * 8 + h) * 256 + qb * 128) * 64;
    const bf* kh = kvn + (size_t)(bt * 16 + h) * 512 * 64;
    const bf* vh = kvn + (size_t)(bt * 16 + 8 + h) * 512 * 64;

    const int srow = tid >> 1;
    const int sseg = (tid & 1) * 32;

    f32x4 o[2][4] = {};
    float sum[2][4] = {};
    bf* Pw = &Ps[wave][0];

    for (int t = 0; t < 4; ++t) {
        {
            const bf* kr = kh + (size_t)(t * 128 + srow) * 64 + sseg;
            bf* kd = Kt + srow * 72 + sseg;
#pragma unroll
            for (int j = 0; j < 4; ++j)
                *(bf16x8*)(kd + j * 8) = *(const bf16x8*)(kr + j * 8);

            const bf* vr = vh + (size_t)(t * 128 + srow) * 64 + sseg;
            bf16x8 vv[4];
#pragma unroll
            for (int j = 0; j < 4; ++j) vv[j] = *(const bf16x8*)(vr + j * 8);
#pragma unroll
            for (int j = 0; j < 4; ++j)
#pragma unroll
                for (int e = 0; e < 8; ++e)
                    Vt[(sseg + j * 8 + e) * 136 + srow] = vv[j][e];
        }
        __syncthreads();

#pragma unroll
        for (int c = 0; c < 2; ++c) {
            const int r0 = wave * 32 + c * 16;
            const bf* qp = qh + (size_t)(r0 + lm) * 64 + quad * 8;
            const bf16x8 a0 = *(const bf16x8*)qp;
            const bf16x8 a1 = *(const bf16x8*)(qp + 32);

            f32x4 s[8];
#pragma unroll
            for (int nt = 0; nt < 8; ++nt) {
                const bf16x8 k0 = *(const bf16x8*)(&Kt[(nt * 16 + lm) * 72 + quad * 8]);
                const bf16x8 k1 = *(const bf16x8*)(&Kt[(nt * 16 + lm) * 72 + 32 + quad * 8]);
                f32x4 z = {};
                z = MFMA(a0, k0, z);
                s[nt] = MFMA(a1, k1, z);
            }

            for (int ntp = 0; ntp < 4; ++ntp) {
#pragma unroll
                for (int tt = 0; tt < 2; ++tt)
#pragma unroll
                    for (int rr = 0; rr < 4; ++rr) {
                        const float e = __expf(s[ntp * 2 + tt][rr] * 0.125f);
                        sum[c][rr] += e;
                        Pw[(quad * 4 + rr) * 40 + tt * 16 + lm] = (bf)e;
                    }
                const bf16x8 ap = *(const bf16x8*)(&Pw[lm * 40 + quad * 8]);
#pragma unroll
                for (int dt = 0; dt < 4; ++dt) {
                    const bf16x8 bv = *(const bf16x8*)(&Vt[(dt * 16 + lm) * 136 + ntp * 32 + quad * 8]);
                    o[c][dt] = MFMA(ap, bv, o[c][dt]);
                }
            }
        }
        __syncthreads();
    }

#pragma unroll
    for (int c = 0; c < 2; ++c) {
        float inv[4];
#pragma unroll
        for (int rr = 0; rr < 4; ++rr) {
            float sm = sum[c][rr];
            sm += __shfl_xor(sm, 1, 64);
            sm += __shfl_xor(sm, 2, 64);
            sm += __shfl_xor(sm, 4, 64);
            sm += __shfl_xor(sm, 8, 64);
            inv[rr] = 1.0f / sm;
        }
        bf* Xp = X + ((size_t)bt * 256 + qb * 128 + wave * 32 + c * 16) * 512 + h * 64;
#pragma unroll
        for (int dt = 0; dt < 4; ++dt)
#pragma unroll
            for (int rr = 0; rr < 4; ++rr)
                Xp[(size_t)(quad * 4 + rr) * 512 + dt * 16 + lm] = (bf)(o[c][dt][rr] * inv[rr]);
    }
}

extern "C" void kernel_launch(void* const* d_in, const int* in_sizes, int n_in,
                              void* d_out, int out_size, void* d_ws, size_t ws_size,
                              hipStream_t stream)
{
    const float* q   = (const float*)d_in[0];  // (8,8,256,512) fp32
    const float* kv  = (const float*)d_in[1];  // (8,8,512,512) fp32
    const float* Wq  = (const float*)d_in[2];  // (512,512) fp32
    const float* bq  = (const float*)d_in[3];  // (512) fp32
    const float* Wkv = (const float*)d_in[4];  // (1024,512) fp32
    const float* bkv = (const float*)d_in[5];  // (1024) fp32
    const float* Wm  = (const float*)d_in[6];  // (512,512) fp32
    const float* bm  = (const float*)d_in[7];  // (512) fp32
    float* out = (float*)d_out;                // (8,8,256,512) fp32 (32 MiB)

    // R7-exact buffer map:
    // ws:   kvb [0,32 MiB) (dead after step 2)      kvn [32,96 MiB)
    //       wqb [0,0.5 MiB) (written step 3, after kvb dead)
    //       wmb [16,16.5 MiB) (written step 3, survives: X is [0,16))
    //       X   [0,16 MiB) (written step 5, after wqb dead)
    // d_out: wkvb [0,1 MiB) (dead after step 2); qb [0,16 MiB) (written step 3);
    //        qn [16,32 MiB); step 6 rewrites all of d_out with fp32 out.
    char* ws = (char*)d_ws;
    bf* kvb = (bf*)ws;
    bf* kvn = (bf*)(ws + (size_t)(32 << 20));
    bf* wqb = (bf*)ws;
    bf* wmb = (bf*)(ws + (size_t)(16 << 20));
    bf* X   = (bf*)ws;
    char* dob = (char*)d_out;
    bf* wkvb = (bf*)dob;
    bf* qb   = (bf*)dob;
    bf* qn   = (bf*)(dob + (size_t)(16 << 20));

    {
        auto k0 = gemmkv<16, 9>;
        (void)hipFuncSetAttribute((const void*)k0, hipFuncAttributeMaxDynamicSharedMemorySize, 65536);
    }

    // 1. kv + Wkv -> bf16
    cvt2<<<dim3(8448), 256, 0, stream>>>(kv, kvb, 2097152, Wkv, wkvb, 65536);
    // 2. KV projection + bias + fused L2-norm -> head-major kvn  [128^2 BK=64 dbuf, 2 blocks/CU]
    gemmkv<16, 9><<<dim3(8, 256), 256, 65536, stream>>>(kvb, wkvb, bkv, kvn, 512);
    // 3. q, Wq, Wm -> bf16
    cvt3<<<dim3(4352), 256, 0, stream>>>(q, qb, 1048576, Wq, wqb, 32768, Wm, wmb, 32768);
    // 4. Q projection + bias + fused L2-norm -> head-major qn  [R0-exact gemm128]
    gemm128<0, 8, 8><<<dim3(128, 4), 256, 0, stream>>>(qb, wqb, bq, nullptr, qn, 16384, 512, 512);
    // 5. no-max flash cosine attention  [R0-exact]
    attn<<<dim3(1024), 256, 0, stream>>>(qn, kvn, X);
    // 6. output projection + bias + fp32 residual -> fp32 out  [R0-exact gemm128]
    gemm128<1, 0, 0><<<dim3(128, 4), 256, 0, stream>>>(X, wmb, bm, q, out, 16384, 512, 512);
}

// Round 11
// 285.986 us; speedup vs baseline: 1.8604x; 1.0057x over previous
//
#include <hip/hip_runtime.h>
#include <hip/hip_bf16.h>

using bf = __bf16;
typedef __attribute__((ext_vector_type(8))) __bf16 bf16x8;
typedef __attribute__((ext_vector_type(4))) float f32x4;

#define MFMA(a, b, c) __builtin_amdgcn_mfma_f32_16x16x32_bf16((a), (b), (c), 0, 0, 0)
#define GLL16(g, s)                                                         \
    __builtin_amdgcn_global_load_lds(                                       \
        (const __attribute__((address_space(1))) void*)(g),                 \
        (__attribute__((address_space(3))) void*)(s), 16, 0, 0)

// ---------------- fp32 -> bf16 converts (merged, 8 elems/thread) ----------------
static __device__ __forceinline__ void cvt_one(const float* __restrict__ s,
                                               bf* __restrict__ d, int i)
{
    const f32x4 a = ((const f32x4*)s)[2 * i];
    const f32x4 b = ((const f32x4*)s)[2 * i + 1];
    bf16x8 r;
#pragma unroll
    for (int k = 0; k < 4; ++k) { r[k] = (bf)a[k]; r[4 + k] = (bf)b[k]; }
    ((bf16x8*)d)[i] = r;
}

__global__ __launch_bounds__(256) void cvt2(const float* __restrict__ s1, bf* __restrict__ d1, int n1,
                                            const float* __restrict__ s2, bf* __restrict__ d2, int n2)
{
    int i = blockIdx.x * 256 + threadIdx.x;
    if (i < n1) { cvt_one(s1, d1, i); return; }
    i -= n1;
    if (i < n2) cvt_one(s2, d2, i);
}

__global__ __launch_bounds__(256) void cvt3(const float* __restrict__ s1, bf* __restrict__ d1, int n1,
                                            const float* __restrict__ s2, bf* __restrict__ d2, int n2,
                                            const float* __restrict__ s3, bf* __restrict__ d3, int n3)
{
    int i = blockIdx.x * 256 + threadIdx.x;
    if (i < n1) { cvt_one(s1, d1, i); return; }
    i -= n1;
    if (i < n2) { cvt_one(s2, d2, i); return; }
    i -= n2;
    if (i < n3) cvt_one(s3, d3, i);
}

// ---------------- m97-style bf16 128x128 GEMM (R0/R7-exact) ----------------
// EPI 0: bias + L2-norm per 64-col head group, bf16 head-major out.
// EPI 1: bias + fp32 residual, fp32 out row-major.
template <int EPI, int GH, int LGR>
__global__ __launch_bounds__(256) void gemm128(
    const bf* __restrict__ A, const bf* __restrict__ W,
    const float* __restrict__ bias, const float* __restrict__ res,
    void* __restrict__ Cout, int M, int N, int K)
{
    __shared__ __attribute__((aligned(16))) bf As[128 * 32];
    __shared__ __attribute__((aligned(16))) bf Bs[128 * 32];

    const int lane = threadIdx.x & 63;
    const int wave = threadIdx.x >> 6;
    const int lm = lane & 15;
    const int quad = lane >> 4;
    const int row0 = blockIdx.x * 128, col0 = blockIdx.y * 128;
    const int wrow = (wave >> 1) * 64, wcol = (wave & 1) * 64;

    const int sr = lane >> 2;            // 0..15
    const int sc = (lane & 3) * 8;       // elem offset 0,8,16,24
    const bf* Ag = A + (size_t)(row0 + wave * 32 + sr) * K + sc;
    const bf* Wg = W + (size_t)(col0 + wave * 32 + sr) * K + sc;
    bf* AsW = As + wave * 1024;
    bf* BsW = Bs + wave * 1024;

    f32x4 acc[4][4] = {};

    for (int k0 = 0; k0 < K; k0 += 32) {
        GLL16(Ag + k0, AsW);
        GLL16(Ag + (size_t)16 * K + k0, AsW + 512);
        GLL16(Wg + k0, BsW);
        GLL16(Wg + (size_t)16 * K + k0, BsW + 512);
        __syncthreads();

        bf16x8 a[4], b[4];
#pragma unroll
        for (int i = 0; i < 4; ++i)
            a[i] = *(const bf16x8*)(As + (wrow + i * 16 + lm) * 32 + quad * 8);
#pragma unroll
        for (int j = 0; j < 4; ++j)
            b[j] = *(const bf16x8*)(Bs + (wcol + j * 16 + lm) * 32 + quad * 8);
#pragma unroll
        for (int i = 0; i < 4; ++i)
#pragma unroll
            for (int j = 0; j < 4; ++j)
                acc[i][j] = MFMA(a[i], b[j], acc[i][j]);
        __syncthreads();
    }

    float bv[4];
#pragma unroll
    for (int j = 0; j < 4; ++j) bv[j] = bias[col0 + wcol + j * 16 + lm];

    if (EPI == 0) {
        bf* C = (bf*)Cout;
        const int g = (col0 + wcol) >> 6;
#pragma unroll
        for (int i = 0; i < 4; ++i) {
#pragma unroll
            for (int rg = 0; rg < 4; ++rg) {
                float v[4];
                float ss = 0.f;
#pragma unroll
                for (int j = 0; j < 4; ++j) {
                    const float x = acc[i][j][rg] + bv[j];
                    v[j] = x;
                    ss += x * x;
                }
                ss += __shfl_xor(ss, 1, 64);
                ss += __shfl_xor(ss, 2, 64);
                ss += __shfl_xor(ss, 4, 64);
                ss += __shfl_xor(ss, 8, 64);
                const float inv = 1.0f / fmaxf(sqrtf(ss), 1e-12f);
                const int row = row0 + wrow + i * 16 + quad * 4 + rg;
                const int bt = row >> LGR;
                const int rl = row & ((1 << LGR) - 1);
                bf* Cr = C + (((size_t)(bt * GH + g) << LGR) + rl) * 64;
#pragma unroll
                for (int j = 0; j < 4; ++j)
                    Cr[j * 16 + lm] = (bf)(v[j] * inv);
            }
        }
    } else {
        float* C = (float*)Cout;
#pragma unroll
        for (int i = 0; i < 4; ++i) {
#pragma unroll
            for (int rg = 0; rg < 4; ++rg) {
                const int row = row0 + wrow + i * 16 + quad * 4 + rg;
#pragma unroll
                for (int j = 0; j < 4; ++j) {
                    const size_t idx = (size_t)row * N + col0 + wcol + j * 16 + lm;
                    C[idx] = acc[i][j][rg] + bv[j] + res[idx];
                }
            }
        }
    }
}

// ---------------- KV GEMM: 128x128 tile, BK=64, dbuf, 2 blocks/CU ----------------
// Body identical to R10 (passed, no spill: WRITE=64MB exactly, acc in AGPRs).
// ONE change: grid transposed to (256,8), blockIdx.x = row-block, blockIdx.y = col-block.
// Dispatch ID D = rowb + colb*256; 256 % 8 == 0 -> all 8 col-blocks of an A-panel have
// D % 8 == rowb % 8 -> SAME XCD -> panel fetched from HBM once, served 8x from its L2.
// (gemm256's grid(128,4) has this property and measures FETCH=39MB; R10's grid(8,256)
//  spread each panel over 8 XCDs and measured FETCH=133MB.)
template <int GH, int LGR>
__global__ __launch_bounds__(256, 2) void gemmkv(
    const bf* __restrict__ A, const bf* __restrict__ W,
    const float* __restrict__ bias, bf* __restrict__ C, int K)
{
    extern __shared__ __attribute__((aligned(16))) char smem[];
    char* Asm = smem;            // [2 buf][128 rows][128 B]
    char* Bsm = smem + 32768;

    const int tid = threadIdx.x;
    const int lane = tid & 63;
    const int lm = lane & 15;
    const int quad = lane >> 4;
    const int wave = tid >> 6;
    const int wm = wave >> 1;        // 0..1 (A half)
    const int wn = wave & 1;         // 0..1 (B half)
    const int row0 = blockIdx.x * 128, col0 = blockIdx.y * 128;
    const int NT = K >> 6;           // 8 tiles of BK=64

    const int tr = tid >> 3;
    const int sswz = (tid & 7) ^ (tr & 7);
    const bf* Ath = A + (size_t)(row0 + tr) * K + sswz * 8;
    const bf* Wth = W + (size_t)(col0 + tr) * K + sswz * 8;
    const int doff = tr * 128 + (tid & 7) * 16;

    const char* aBase = Asm + (wm * 64 + lm) * 128;
    const char* bBase = Bsm + (wn * 64 + lm) * 128;
    const int skz0 = ((quad ^ (lm & 7)) << 4);
    const int skz1 = (((4 + quad) ^ (lm & 7)) << 4);

    f32x4 acc[4][4] = {};

    auto stage = [&](int kt) {
        const int bo = (kt & 1) * 16384;
        const int ko = kt * 64;
#pragma unroll
        for (int i = 0; i < 4; ++i) {
            GLL16(Ath + (size_t)(32 * i) * K + ko, Asm + bo + i * 4096 + doff);
            GLL16(Wth + (size_t)(32 * i) * K + ko, Bsm + bo + i * 4096 + doff);
        }
    };

    // prologue: tile 0 into buf0
    stage(0);
    __syncthreads();

    for (int t = 0; t < NT; ++t) {
        if (t + 1 < NT) stage(t + 1);       // opposite buffer: race-free
        const int bo = (t & 1) * 16384;
        bf16x8 a[4], b[4];
#pragma unroll
        for (int f = 0; f < 4; ++f) {
            a[f] = *(const bf16x8*)(aBase + bo + f * 2048 + skz0);
            b[f] = *(const bf16x8*)(bBase + bo + f * 2048 + skz0);
        }
        __builtin_amdgcn_s_setprio(1);
#pragma unroll
        for (int f = 0; f < 4; ++f)
#pragma unroll
            for (int j = 0; j < 4; ++j)
                acc[f][j] = MFMA(a[f], b[j], acc[f][j]);
        __builtin_amdgcn_s_setprio(0);
#pragma unroll
        for (int f = 0; f < 4; ++f) {
            a[f] = *(const bf16x8*)(aBase + bo + f * 2048 + skz1);
            b[f] = *(const bf16x8*)(bBase + bo + f * 2048 + skz1);
        }
        __builtin_amdgcn_s_setprio(1);
#pragma unroll
        for (int f = 0; f < 4; ++f)
#pragma unroll
            for (int j = 0; j < 4; ++j)
                acc[f][j] = MFMA(a[f], b[j], acc[f][j]);
        __builtin_amdgcn_s_setprio(0);
        __syncthreads();                    // drains vmcnt(0): tile t+1 landed
    }

    // ---- epilogue: bias + L2-norm per 64-col head, head-major bf16 out ----
    const int wrow = wm * 64, wcol = wn * 64;
    float bv[4];
#pragma unroll
    for (int j = 0; j < 4; ++j) bv[j] = bias[col0 + wcol + j * 16 + lm];
    const int g = (col0 + wcol) >> 6;
#pragma unroll
    for (int i = 0; i < 4; ++i) {
#pragma unroll
        for (int rg = 0; rg < 4; ++rg) {
            float v[4];
            float ss = 0.f;
#pragma unroll
            for (int j = 0; j < 4; ++j) {
                const float x = acc[i][j][rg] + bv[j];
                v[j] = x;
                ss += x * x;
            }
            ss += __shfl_xor(ss, 1, 64);
            ss += __shfl_xor(ss, 2, 64);
            ss += __shfl_xor(ss, 4, 64);
            ss += __shfl_xor(ss, 8, 64);
            const float inv = 1.0f / fmaxf(sqrtf(ss), 1e-12f);
            const int row = row0 + wrow + i * 16 + quad * 4 + rg;
            const int bt = row >> LGR;
            const int rl = row & ((1 << LGR) - 1);
            bf* Cr = C + (((size_t)(bt * GH + g) << LGR) + rl) * 64;
#pragma unroll
            for (int j = 0; j < 4; ++j)
                Cr[j * 16 + lm] = (bf)(v[j] * inv);
        }
    }
}

// ---------------- flash-style cosine attention, NO-MAX softmax (R0-exact) ----------------
__global__ __launch_bounds__(256, 4) void attn(
    const bf* __restrict__ qn, const bf* __restrict__ kvn, bf* __restrict__ X)
{
    __shared__ __attribute__((aligned(16))) bf Kt[128 * 72];
    __shared__ __attribute__((aligned(16))) bf Vt[64 * 136];
    __shared__ __attribute__((aligned(16))) bf Ps[4][16 * 40];

    const int qb = blockIdx.x >> 9;
    const int rb = blockIdx.x & 511;
    const int bt = rb >> 3;
    const int h = rb & 7;
    const int tid = threadIdx.x;
    const int lane = tid & 63;
    const int wave = tid >> 6;
    const int lm = lane & 15;
    const int quad = lane >> 4;

    const bf* qh = qn + ((size_t)(bt * 8 + h) * 256 + qb * 128) * 64;
    const bf* kh = kvn + (size_t)(bt * 16 + h) * 512 * 64;
    const bf* vh = kvn + (size_t)(bt * 16 + 8 + h) * 512 * 64;

    const int srow = tid >> 1;
    const int sseg = (tid & 1) * 32;

    f32x4 o[2][4] = {};
    float sum[2][4] = {};
    bf* Pw = &Ps[wave][0];

    for (int t = 0; t < 4; ++t) {
        {
            const bf* kr = kh + (size_t)(t * 128 + srow) * 64 + sseg;
            bf* kd = Kt + srow * 72 + sseg;
#pragma unroll
            for (int j = 0; j < 4; ++j)
                *(bf16x8*)(kd + j * 8) = *(const bf16x8*)(kr + j * 8);

            const bf* vr = vh + (size_t)(t * 128 + srow) * 64 + sseg;
            bf16x8 vv[4];
#pragma unroll
            for (int j = 0; j < 4; ++j) vv[j] = *(const bf16x8*)(vr + j * 8);
#pragma unroll
            for (int j = 0; j < 4; ++j)
#pragma unroll
                for (int e = 0; e < 8; ++e)
                    Vt[(sseg + j * 8 + e) * 136 + srow] = vv[j][e];
        }
        __syncthreads();

#pragma unroll
        for (int c = 0; c < 2; ++c) {
            const int r0 = wave * 32 + c * 16;
            const bf* qp = qh + (size_t)(r0 + lm) * 64 + quad * 8;
            const bf16x8 a0 = *(const bf16x8*)qp;
            const bf16x8 a1 = *(const bf16x8*)(qp + 32);

            f32x4 s[8];
#pragma unroll
            for (int nt = 0; nt < 8; ++nt) {
                const bf16x8 k0 = *(const bf16x8*)(&Kt[(nt * 16 + lm) * 72 + quad * 8]);
                const bf16x8 k1 = *(const bf16x8*)(&Kt[(nt * 16 + lm) * 72 + 32 + quad * 8]);
                f32x4 z = {};
                z = MFMA(a0, k0, z);
                s[nt] = MFMA(a1, k1, z);
            }

            for (int ntp = 0; ntp < 4; ++ntp) {
#pragma unroll
                for (int tt = 0; tt < 2; ++tt)
#pragma unroll
                    for (int rr = 0; rr < 4; ++rr) {
                        const float e = __expf(s[ntp * 2 + tt][rr] * 0.125f);
                        sum[c][rr] += e;
                        Pw[(quad * 4 + rr) * 40 + tt * 16 + lm] = (bf)e;
                    }
                const bf16x8 ap = *(const bf16x8*)(&Pw[lm * 40 + quad * 8]);
#pragma unroll
                for (int dt = 0; dt < 4; ++dt) {
                    const bf16x8 bv = *(const bf16x8*)(&Vt[(dt * 16 + lm) * 136 + ntp * 32 + quad * 8]);
                    o[c][dt] = MFMA(ap, bv, o[c][dt]);
                }
            }
        }
        __syncthreads();
    }

#pragma unroll
    for (int c = 0; c < 2; ++c) {
        float inv[4];
#pragma unroll
        for (int rr = 0; rr < 4; ++rr) {
            float sm = sum[c][rr];
            sm += __shfl_xor(sm, 1, 64);
            sm += __shfl_xor(sm, 2, 64);
            sm += __shfl_xor(sm, 4, 64);
            sm += __shfl_xor(sm, 8, 64);
            inv[rr] = 1.0f / sm;
        }
        bf* Xp = X + ((size_t)bt * 256 + qb * 128 + wave * 32 + c * 16) * 512 + h * 64;
#pragma unroll
        for (int dt = 0; dt < 4; ++dt)
#pragma unroll
            for (int rr = 0; rr < 4; ++rr)
                Xp[(size_t)(quad * 4 + rr) * 512 + dt * 16 + lm] = (bf)(o[c][dt][rr] * inv[rr]);
    }
}

extern "C" void kernel_launch(void* const* d_in, const int* in_sizes, int n_in,
                              void* d_out, int out_size, void* d_ws, size_t ws_size,
                              hipStream_t stream)
{
    const float* q   = (const float*)d_in[0];  // (8,8,256,512) fp32
    const float* kv  = (const float*)d_in[1];  // (8,8,512,512) fp32
    const float* Wq  = (const float*)d_in[2];  // (512,512) fp32
    const float* bq  = (const float*)d_in[3];  // (512) fp32
    const float* Wkv = (const float*)d_in[4];  // (1024,512) fp32
    const float* bkv = (const float*)d_in[5];  // (1024) fp32
    const float* Wm  = (const float*)d_in[6];  // (512,512) fp32
    const float* bm  = (const float*)d_in[7];  // (512) fp32
    float* out = (float*)d_out;                // (8,8,256,512) fp32 (32 MiB)

    // R7-exact buffer map:
    // ws:   kvb [0,32 MiB) (dead after step 2)      kvn [32,96 MiB)
    //       wqb [0,0.5 MiB) (written step 3, after kvb dead)
    //       wmb [16,16.5 MiB) (written step 3, survives: X is [0,16))
    //       X   [0,16 MiB) (written step 5, after wqb dead)
    // d_out: wkvb [0,1 MiB) (dead after step 2); qb [0,16 MiB) (written step 3);
    //        qn [16,32 MiB); step 6 rewrites all of d_out with fp32 out.
    char* ws = (char*)d_ws;
    bf* kvb = (bf*)ws;
    bf* kvn = (bf*)(ws + (size_t)(32 << 20));
    bf* wqb = (bf*)ws;
    bf* wmb = (bf*)(ws + (size_t)(16 << 20));
    bf* X   = (bf*)ws;
    char* dob = (char*)d_out;
    bf* wkvb = (bf*)dob;
    bf* qb   = (bf*)dob;
    bf* qn   = (bf*)(dob + (size_t)(16 << 20));

    {
        auto k0 = gemmkv<16, 9>;
        (void)hipFuncSetAttribute((const void*)k0, hipFuncAttributeMaxDynamicSharedMemorySize, 65536);
    }

    // 1. kv + Wkv -> bf16
    cvt2<<<dim3(8448), 256, 0, stream>>>(kv, kvb, 2097152, Wkv, wkvb, 65536);
    // 2. KV projection + bias + fused L2-norm -> head-major kvn
    //    [128^2 BK=64 dbuf, 2 blocks/CU; XCD-aligned grid: col-blocks of a panel on one XCD]
    gemmkv<16, 9><<<dim3(256, 8), 256, 65536, stream>>>(kvb, wkvb, bkv, kvn, 512);
    // 3. q, Wq, Wm -> bf16
    cvt3<<<dim3(4352), 256, 0, stream>>>(q, qb, 1048576, Wq, wqb, 32768, Wm, wmb, 32768);
    // 4. Q projection + bias + fused L2-norm -> head-major qn  [R0-exact gemm128]
    gemm128<0, 8, 8><<<dim3(128, 4), 256, 0, stream>>>(qb, wqb, bq, nullptr, qn, 16384, 512, 512);
    // 5. no-max flash cosine attention  [R0-exact]
    attn<<<dim3(1024), 256, 0, stream>>>(qn, kvn, X);
    // 6. output projection + bias + fp32 residual -> fp32 out  [R0-exact gemm128]
    gemm128<1, 0, 0><<<dim3(128, 4), 256, 0, stream>>>(X, wmb, bm, q, out, 16384, 512, 512);
}